// Round 4
// baseline (3442.592 us; speedup 1.0000x reference)
//
#include <hip/hip_runtime.h>
#include <math.h>

#define TB 256

__device__ __forceinline__ float fast_sigmoid(float x) {
    return 1.0f / (1.0f + __expf(-x));
}
__device__ __forceinline__ float fast_tanh(float x) {
    float a = fabsf(x);
    float e = __expf(2.0f * a);
    float r = 1.0f - 2.0f / (e + 1.0f);
    return copysignf(r, x);
}
__device__ __forceinline__ float gelu_exact(float x) {
    return 0.5f * x * (1.0f + erff(x * 0.70710678118654752f));
}

// ---------------------------------------------------------------------------
// Kernel A: wave-specialized pipelined recurrent core.
// 512 blocks x 256 threads (4 waves), one block per batch element.
// Wave 0: the serial slot-attention chain for step t (slots in registers,
//   cross-lane via shfl; no intra-wave barriers needed).
// Waves 1-3: conv(t+1) [phase 1] and KQV GEMM(t+1) + X(t+2) load [phase 2].
// Exactly 2 __syncthreads per step. Fused weights as in round 2 (verified):
//   Mkq[d][dp] = sum_e k_w[e][d] q_w[e][dp]
//   MvW[d][e]  = sum_e' v_w[e'][d] wih[e][e']
//   A12[c][col] = sum_d wts[d][c] * (col<32 ? Mkq[d][col] : MvW[d][col-32])
//   c12[col]    = sum_d bts[d]   * (same)
// ---------------------------------------------------------------------------
__global__ __launch_bounds__(256, 2) void slot_recur_pipe(
    const float* __restrict__ frames, const float* __restrict__ slot_mu,
    const float* __restrict__ conv_w, const float* __restrict__ conv_b,
    const float* __restrict__ to_slot_w, const float* __restrict__ to_slot_b,
    const float* __restrict__ q_w, const float* __restrict__ k_w,
    const float* __restrict__ v_w,
    const float* __restrict__ wih, const float* __restrict__ whh,
    const float* __restrict__ bih, const float* __restrict__ bhh,
    float* __restrict__ slots_out)
{
    const int tid = threadIdx.x;
    const int b = blockIdx.x;
    const int lane = tid & 63;
    const int wid = tid >> 6;
    const int tid1 = tid - 64;          // waves 1-3 index (valid when wid>0)
    const int s_id = lane >> 4, u = lane & 15;

    __shared__ float A12_s[32 * 128];   // [c][col], stride 128
    __shared__ float c12_s[128];
    __shared__ float whh_s[96 * 36];    // [e][d], pad 36
    __shared__ float vWT_s[2][96 * 20]; // [e][n], pad 20, double-buffered
    __shared__ float kq_s[16 * 36];     // [n][d]
    __shared__ float X_s[16 * 36];      // [n][k], k = half*16 + p*4 + q
    __shared__ float feat_s[16 * 36];   // [n][c]
    __shared__ float bih_s[96], bhh_s[96];
    __shared__ float Mkq_s[1024];       // setup temp
    __shared__ float scr_s[4096];       // setup temp: wts[0..1024), MvW[1024..4096)

    const float* fb = frames + (size_t)b * (128 * 256);

    // ---- Setup S0: stage raw weights
    for (int i = tid; i < 3072; i += 256) A12_s[i] = wih[i];   // wih staged in A12 area
    for (int i = tid; i < 1024; i += 256) {
        whh_s[i]        = v_w[i];
        whh_s[1024 + i] = k_w[i];
        whh_s[2048 + i] = q_w[i];
        scr_s[i]        = to_slot_w[i];                        // wts staged
    }
    __syncthreads();

    // ---- Setup S1: Mkq, MvW
    for (int o = tid; o < 1024; o += 256) {
        int d = o >> 5, dp = o & 31;
        float acc = 0.f;
#pragma unroll 8
        for (int e = 0; e < 32; ++e)
            acc += whh_s[1024 + e * 32 + d] * whh_s[2048 + e * 32 + dp];
        Mkq_s[o] = acc;
    }
    for (int o = tid; o < 3072; o += 256) {
        int d = o / 96, e = o - d * 96;
        float acc = 0.f;
#pragma unroll 8
        for (int ep = 0; ep < 32; ++ep)
            acc += whh_s[ep * 32 + d] * A12_s[e * 32 + ep];
        scr_s[1024 + d * 96 + e] = acc;
    }
    __syncthreads();

    // ---- Setup S2: A12/c12, real whh, biases, X(step 0)
    for (int o = tid; o < 4096; o += 256) {
        int c = o >> 7, col = o & 127;
        float acc = 0.f;
        if (col < 32) {
#pragma unroll 8
            for (int d = 0; d < 32; ++d) acc += scr_s[d * 32 + c] * Mkq_s[d * 32 + col];
        } else {
            int e = col - 32;
#pragma unroll 8
            for (int d = 0; d < 32; ++d) acc += scr_s[d * 32 + c] * scr_s[1024 + d * 96 + e];
        }
        A12_s[c * 128 + col] = acc;
    }
    if (tid < 128) {
        int col = tid;
        float acc = 0.f;
        if (col < 32) {
            for (int d = 0; d < 32; ++d) acc += to_slot_b[d] * Mkq_s[d * 32 + col];
        } else {
            int e = col - 32;
            for (int d = 0; d < 32; ++d) acc += to_slot_b[d] * scr_s[1024 + d * 96 + e];
        }
        c12_s[col] = acc;
    }
    for (int i = tid; i < 3072; i += 256) whh_s[(i >> 5) * 36 + (i & 31)] = whh[i];
    if (tid < 96) { bih_s[tid] = bih[tid]; bhh_s[tid] = bhh[tid]; }

    auto load_X = [&](int idx, int step) {
        int i = idx >> 2, j4 = idx & 3;
        float4 c4 = *(const float4*)&fb[(size_t)(step + 1) * 256 + i * 16 + j4 * 4];
        float4 p4 = *(const float4*)&fb[(size_t)step * 256 + i * 16 + j4 * 4];
        int n = (i >> 2) * 4 + j4, p = i & 3;
        *(float4*)&X_s[n * 36 + p * 4] = c4;
        *(float4*)&X_s[n * 36 + 16 + p * 4] = p4;
    };
    if (tid < 64) load_X(tid, 0);

    // per-thread persistent registers
    float h0 = slot_mu[s_id * 32 + u];        // wave0: slot state
    float h1 = slot_mu[s_id * 32 + u + 16];
    float cw[32];                              // waves1-3: conv weight row
    float cb = 0.f;
    if (wid > 0) {
        int o = tid1 & 31;
        const float* wp = conv_w + o * 32;
#pragma unroll
        for (int k = 0; k < 32; k += 4) {
            float4 v = *(const float4*)&wp[k];
            cw[k] = v.x; cw[k + 1] = v.y; cw[k + 2] = v.z; cw[k + 3] = v.w;
        }
        cb = conv_b[o];
    }
    __syncthreads();

    // ---- Prologue: conv(step 0) with all threads
    {
        int o = tid & 31;
        float pw[32];
        const float* wp = conv_w + o * 32;
#pragma unroll
        for (int k = 0; k < 32; k += 4) {
            float4 v = *(const float4*)&wp[k];
            pw[k] = v.x; pw[k + 1] = v.y; pw[k + 2] = v.z; pw[k + 3] = v.w;
        }
        float pcb = conv_b[o];
        for (int i = tid; i < 512; i += 256) {
            int n = i >> 5;
            const float* xr = &X_s[n * 36];
            float acc = pcb;
#pragma unroll
            for (int k = 0; k < 32; k += 4) {
                float4 x4 = *(const float4*)&xr[k];
                acc += pw[k] * x4.x + pw[k + 1] * x4.y + pw[k + 2] * x4.z + pw[k + 3] * x4.w;
            }
            feat_s[n * 36 + o] = gelu_exact(acc);
        }
    }
    __syncthreads();

    auto gemm_task = [&](int task, float* vWTb) {
        int c0 = (task >> 1) << 1;
        int r0 = (task & 1) * 8;
        float accx[8], accy[8];
#pragma unroll
        for (int r = 0; r < 8; ++r) { accx[r] = 0.f; accy[r] = 0.f; }
#pragma unroll
        for (int c4 = 0; c4 < 8; ++c4) {
            float2 a0 = *(const float2*)&A12_s[(c4 * 4 + 0) * 128 + c0];
            float2 a1 = *(const float2*)&A12_s[(c4 * 4 + 1) * 128 + c0];
            float2 a2 = *(const float2*)&A12_s[(c4 * 4 + 2) * 128 + c0];
            float2 a3 = *(const float2*)&A12_s[(c4 * 4 + 3) * 128 + c0];
#pragma unroll
            for (int r = 0; r < 8; ++r) {
                float4 f = *(const float4*)&feat_s[(r0 + r) * 36 + c4 * 4];
                accx[r] += f.x * a0.x + f.y * a1.x + f.z * a2.x + f.w * a3.x;
                accy[r] += f.x * a0.y + f.y * a1.y + f.z * a2.y + f.w * a3.y;
            }
        }
        float cx = c12_s[c0], cy = c12_s[c0 + 1];
        if (c0 < 32) {
#pragma unroll
            for (int r = 0; r < 8; ++r)
                *(float2*)&kq_s[(r0 + r) * 36 + c0] =
                    make_float2(accx[r] + cx, accy[r] + cy);
        } else {
            int e0 = c0 - 32;
#pragma unroll
            for (int r = 0; r < 8; ++r) {
                vWTb[e0 * 20 + r0 + r] = accx[r] + cx;
                vWTb[(e0 + 1) * 20 + r0 + r] = accy[r] + cy;
            }
        }
    };

    // ---- Prologue: KQV(step 0) + X(step 1)
    if (tid < 128) gemm_task(tid, &vWT_s[0][0]);
    else if (tid < 192) load_X(tid - 128, 1);
    __syncthreads();

    float* so = slots_out + (size_t)b * (126 * 128);
    float kr[32];
    int curb = 0;

    // wave-0 attention iteration (wave-internal; no barriers)
    auto attn_iter = [&](const float* vWTb) {
        float sr[32];
#pragma unroll
        for (int k = 0; k < 16; ++k) sr[k] = __shfl(h0, s_id * 16 + k);
#pragma unroll
        for (int k = 0; k < 16; ++k) sr[16 + k] = __shfl(h1, s_id * 16 + k);
        float lg = 0.f;
#pragma unroll
        for (int k = 0; k < 32; ++k) lg += sr[k] * kr[k];
        lg *= 0.17677669529663687f;   // 1/sqrt(32)
        float m = fmaxf(lg, __shfl_xor(lg, 16));
        m = fmaxf(m, __shfl_xor(m, 32));
        float e = __expf(lg - m);
        float ss = e + __shfl_xor(e, 16);
        ss += __shfl_xor(ss, 32);
        float at = e / ss;
        float gh[6];
#pragma unroll
        for (int j = 0; j < 6; ++j) {
            int ee = u + 16 * j;
            const float* wr = &whh_s[ee * 36];
            float acc = bhh_s[ee];
#pragma unroll
            for (int k = 0; k < 32; k += 4) {
                float4 w4 = *(const float4*)&wr[k];
                acc += sr[k] * w4.x + sr[k + 1] * w4.y + sr[k + 2] * w4.z + sr[k + 3] * w4.w;
            }
            gh[j] = acc;
        }
        float ar[16];
#pragma unroll
        for (int n = 0; n < 16; ++n) ar[n] = __shfl(at, s_id * 16 + n);
        float gi[6];
#pragma unroll
        for (int j = 0; j < 6; ++j) {
            int ee = u + 16 * j;
            const float* vr = &vWTb[ee * 20];
            float acc = bih_s[ee];
#pragma unroll
            for (int n = 0; n < 16; n += 4) {
                float4 v4 = *(const float4*)&vr[n];
                acc += ar[n] * v4.x + ar[n + 1] * v4.y + ar[n + 2] * v4.z + ar[n + 3] * v4.w;
            }
            gi[j] = acc;
        }
        float r0g = fast_sigmoid(gi[0] + gh[0]);
        float r1g = fast_sigmoid(gi[1] + gh[1]);
        float z0g = fast_sigmoid(gi[2] + gh[2]);
        float z1g = fast_sigmoid(gi[3] + gh[3]);
        float n0g = fast_tanh(gi[4] + r0g * gh[4]);
        float n1g = fast_tanh(gi[5] + r1g * gh[5]);
        h0 = (1.f - z0g) * n0g + z0g * h0;
        h1 = (1.f - z1g) * n1g + z1g * h1;
    };

#pragma unroll 1
    for (int t = 0; t < 126; ++t) {
        const float* vcur = &vWT_s[curb][0];
        float* vnxt = &vWT_s[curb ^ 1][0];

        // ---- phase 1: wave0 iters 0,1 ; waves1-3 conv(t+1)
        if (wid == 0) {
#pragma unroll
            for (int k = 0; k < 32; k += 4) {
                float4 v = *(const float4*)&kq_s[u * 36 + k];
                kr[k] = v.x; kr[k + 1] = v.y; kr[k + 2] = v.z; kr[k + 3] = v.w;
            }
            attn_iter(vcur);
            attn_iter(vcur);
        } else if (t < 125) {
            int o = tid1 & 31;
            for (int i = tid1; i < 512; i += 192) {
                int n = i >> 5;
                const float* xr = &X_s[n * 36];
                float acc = cb;
#pragma unroll
                for (int k = 0; k < 32; k += 4) {
                    float4 x4 = *(const float4*)&xr[k];
                    acc += cw[k] * x4.x + cw[k + 1] * x4.y + cw[k + 2] * x4.z + cw[k + 3] * x4.w;
                }
                feat_s[n * 36 + o] = gelu_exact(acc);
            }
        }
        __syncthreads();

        // ---- phase 2: wave0 iter 2 + output ; waves1-3 GEMM(t+1) + X(t+2)
        if (wid == 0) {
            attn_iter(vcur);
            so[t * 128 + s_id * 32 + u] = h0;
            so[t * 128 + s_id * 32 + u + 16] = h1;
        } else {
            if (tid1 < 128) {
                if (t < 125) gemm_task(tid1, vnxt);
            } else if (t < 124) {
                load_X(tid1 - 128, t + 2);
            }
        }
        __syncthreads();
        curb ^= 1;
    }
}

// ---------------------------------------------------------------------------
// Kernel B: batched decode. GEMM (64512 x 512) = slots_traj (64512 x 128) @
// dec_w^T, fused deconv(4x4,s4) + tanh + add curr + clip. 32 rows per block.
// ---------------------------------------------------------------------------
__global__ __launch_bounds__(TB, 1) void decode_kernel(
    const float* __restrict__ slots_traj, const float* __restrict__ frames,
    const float* __restrict__ dec_w, const float* __restrict__ dec_b,
    const float* __restrict__ deconv_w, const float* __restrict__ deconv_b,
    float* __restrict__ out)
{
    const int tid = threadIdx.x;
    const int m0 = blockIdx.x * 32;

    __shared__ float sl_s[32 * 132];
    __shared__ float wch_s[64 * 132];
    __shared__ float dw_s[512];
    __shared__ float db_s[512];

    for (int i = tid * 4; i < 32 * 128; i += TB * 4) {
        float4 v = *(const float4*)&slots_traj[(size_t)m0 * 128 + i];
        int r = i >> 7, k = i & 127;
        *(float4*)&sl_s[r * 132 + k] = v;
    }
    for (int i = tid; i < 512; i += TB) {
        dw_s[i] = deconv_w[i];
        db_s[i] = dec_b[i];
    }
    __syncthreads();

    const int cg = tid & 63;
    const int rg = tid >> 6;

    float acc[8][8];
#pragma unroll
    for (int ci = 0; ci < 8; ++ci)
#pragma unroll
        for (int rr = 0; rr < 8; ++rr) acc[ci][rr] = 0.f;

    const float* slb = &sl_s[(rg * 8) * 132];

#pragma unroll
    for (int ch = 0; ch < 8; ++ch) {
        for (int i = tid * 4; i < 64 * 128; i += TB * 4) {
            float4 v = *(const float4*)&dec_w[(size_t)ch * 8192 + i];
            int cl = i >> 7, k = i & 127;
            *(float4*)&wch_s[cl * 132 + k] = v;
        }
        __syncthreads();
        const float* wrow = &wch_s[cg * 132];
#pragma unroll 4
        for (int k = 0; k < 128; k += 4) {
            float4 w4 = *(const float4*)&wrow[k];
#pragma unroll
            for (int rr = 0; rr < 8; ++rr) {
                float4 s4 = *(const float4*)&slb[rr * 132 + k];
                acc[ch][rr] += w4.x * s4.x + w4.y * s4.y + w4.z * s4.z + w4.w * s4.w;
            }
        }
        __syncthreads();
    }

#pragma unroll
    for (int ci = 0; ci < 8; ++ci) {
        float bo = db_s[cg + 64 * ci];
#pragma unroll
        for (int rr = 0; rr < 8; ++rr) acc[ci][rr] += bo;
    }

    const int c0 = cg >> 4;
    const int sp = cg & 15;
    const int bi = sp >> 2, bj = sp & 3;
    const float db0 = deconv_b[0];

#pragma unroll 1
    for (int rr = 0; rr < 8; ++rr) {
        float part[16];
#pragma unroll
        for (int kl = 0; kl < 16; ++kl) part[kl] = 0.f;
#pragma unroll
        for (int m = 0; m < 8; ++m) {
            float sf = acc[m][rr];
            const float* dwp = &dw_s[(c0 + 4 * m) * 16];
#pragma unroll
            for (int kl = 0; kl < 16; ++kl) part[kl] += sf * dwp[kl];
        }
#pragma unroll
        for (int kl = 0; kl < 16; ++kl) {
            part[kl] += __shfl_xor(part[kl], 16);
            part[kl] += __shfl_xor(part[kl], 32);
        }
        if (c0 == 0) {
            int mrow = m0 + rg * 8 + rr;
            int bb = mrow / 126, tt = mrow - bb * 126;
            const float* fr = frames + ((size_t)bb * 128 + (tt + 1)) * 256;
            float* op = out + (size_t)mrow * 256;
#pragma unroll
            for (int kk = 0; kk < 4; ++kk) {
                int pixb = (bi * 4 + kk) * 16 + bj * 4;
                float4 c4 = *(const float4*)&fr[pixb];
                float4 o4;
                o4.x = fminf(fmaxf(c4.x + tanhf(part[kk * 4 + 0] + db0), 0.f), 1.f);
                o4.y = fminf(fmaxf(c4.y + tanhf(part[kk * 4 + 1] + db0), 0.f), 1.f);
                o4.z = fminf(fmaxf(c4.z + tanhf(part[kk * 4 + 2] + db0), 0.f), 1.f);
                o4.w = fminf(fmaxf(c4.w + tanhf(part[kk * 4 + 3] + db0), 0.f), 1.f);
                *(float4*)&op[pixb] = o4;
            }
        }
    }
}

extern "C" void kernel_launch(void* const* d_in, const int* in_sizes, int n_in,
                              void* d_out, int out_size, void* d_ws, size_t ws_size,
                              hipStream_t stream) {
    const float* frames    = (const float*)d_in[0];
    const float* slot_mu   = (const float*)d_in[1];
    const float* conv_w    = (const float*)d_in[2];
    const float* conv_b    = (const float*)d_in[3];
    const float* to_slot_w = (const float*)d_in[4];
    const float* to_slot_b = (const float*)d_in[5];
    const float* q_w       = (const float*)d_in[6];
    const float* k_w       = (const float*)d_in[7];
    const float* v_w       = (const float*)d_in[8];
    const float* gru_wih   = (const float*)d_in[9];
    const float* gru_whh   = (const float*)d_in[10];
    const float* gru_bih   = (const float*)d_in[11];
    const float* gru_bhh   = (const float*)d_in[12];
    const float* dec_w     = (const float*)d_in[13];
    const float* dec_b     = (const float*)d_in[14];
    const float* deconv_w  = (const float*)d_in[15];
    const float* deconv_b  = (const float*)d_in[16];

    float* slots_traj = (float*)d_ws;  // 512*126*128 floats = 33 MB
    float* outp = (float*)d_out;

    hipLaunchKernelGGL(slot_recur_pipe, dim3(512), dim3(256), 0, stream,
                       frames, slot_mu, conv_w, conv_b, to_slot_w, to_slot_b,
                       q_w, k_w, v_w, gru_wih, gru_whh, gru_bih, gru_bhh,
                       slots_traj);
    hipLaunchKernelGGL(decode_kernel, dim3(64512 / 32), dim3(TB), 0, stream,
                       slots_traj, frames, dec_w, dec_b, deconv_w, deconv_b,
                       outp);
}

// Round 5
// 1909.562 us; speedup vs baseline: 1.8028x; 1.8028x over previous
//
#include <hip/hip_runtime.h>
#include <math.h>

#define TB 256

__device__ __forceinline__ float fast_sigmoid(float x) {
    return 1.0f / (1.0f + __expf(-x));
}
__device__ __forceinline__ float fast_tanh(float x) {
    float a = fabsf(x);
    float e = __expf(2.0f * a);
    float r = 1.0f - 2.0f / (e + 1.0f);
    return copysignf(r, x);
}
__device__ __forceinline__ float gelu_exact(float x) {
    return 0.5f * x * (1.0f + erff(x * 0.70710678118654752f));
}

// LDS pool offsets (floats). Runtime arrays and setup temps are aliased:
// setup stages raw weights / Mkq / MvW in regions that later hold convW/kq/vWT.
#define OFF_A12   0        // 4096 : A12 [c][col] stride 128   (setup: staged wih)
#define OFF_C12   4096     // 128
#define OFF_WHH   4224     // 3456 : whh [e][d] stride 36      (setup: staged v/k/q)
#define OFF_BIH   7680     // 96
#define OFF_BHH   7776     // 96
#define OFF_CONVW 7872     // 1152 : convW [o][k] stride 36    (setup: staged wts)
#define OFF_X     9024     // 576  : X [n][k] stride 36
#define OFF_FEAT  9600     // 576  : feat [n][c] stride 36
#define OFF_KQ    10176    // 2*576: kq dbuf [n][d] stride 36  (setup: Mkq 1024)
#define OFF_VWT   11328    // 2*1920: vWT dbuf [e][n] stride 20 (setup: MvW 3072)
#define POOL_SZ   15168    // 60672 bytes

// ---------------------------------------------------------------------------
// Kernel A: wave-specialized pipelined recurrent core (round-4 structure,
// spill-proofed). 512 blocks x 256 threads, one block per batch element.
// Wave 0: serial slot-attention chain (slots in 2 regs/lane, cross-lane via
//   shfl, weights via broadcast LDS reads). Waves 1-3: conv(t+1) [phase 1],
//   KQV GEMM(t+1) + X(t+2) [phase 2]. 2 __syncthreads per step.
// Fused weights (verified rounds 2-4):
//   Mkq[d][dp] = sum_e k_w[e][d] q_w[e][dp]
//   MvW[d][e]  = sum_e' v_w[e'][d] wih[e][e']
//   A12[c][col] = sum_d wts[d][c] * (col<32 ? Mkq[d][col] : MvW[d][col-32])
//   c12[col]    = sum_d bts[d]   * (same)
// ---------------------------------------------------------------------------
__global__ __launch_bounds__(256, 1) void slot_recur_pipe(
    const float* __restrict__ frames, const float* __restrict__ slot_mu,
    const float* __restrict__ conv_w, const float* __restrict__ conv_b,
    const float* __restrict__ to_slot_w, const float* __restrict__ to_slot_b,
    const float* __restrict__ q_w, const float* __restrict__ k_w,
    const float* __restrict__ v_w,
    const float* __restrict__ wih, const float* __restrict__ whh,
    const float* __restrict__ bih, const float* __restrict__ bhh,
    float* __restrict__ slots_out)
{
    const int tid = threadIdx.x;
    const int b = blockIdx.x;
    const int lane = tid & 63;
    const int wid = tid >> 6;
    const int tid1 = tid - 64;          // waves 1-3 index
    const int s_id = lane >> 4, u = lane & 15;

    __shared__ float pool[POOL_SZ];

    const float* fb = frames + (size_t)b * (128 * 256);

    // ---- Setup S0: stage raw weights into aliased regions
    for (int i = tid; i < 3072; i += 256) pool[OFF_A12 + i] = wih[i];
    for (int i = tid; i < 1024; i += 256) {
        pool[OFF_WHH + i]        = v_w[i];
        pool[OFF_WHH + 1024 + i] = k_w[i];
        pool[OFF_WHH + 2048 + i] = q_w[i];
        pool[OFF_CONVW + i]      = to_slot_w[i];
    }
    __syncthreads();

    // ---- Setup S1: Mkq (-> kq region), MvW (-> vWT region)
    for (int o = tid; o < 1024; o += 256) {
        int d = o >> 5, dp = o & 31;
        float acc = 0.f;
#pragma unroll 8
        for (int e = 0; e < 32; ++e)
            acc += pool[OFF_WHH + 1024 + e * 32 + d] * pool[OFF_WHH + 2048 + e * 32 + dp];
        pool[OFF_KQ + o] = acc;
    }
    for (int o = tid; o < 3072; o += 256) {
        int d = o / 96, e = o - d * 96;
        float acc = 0.f;
#pragma unroll 8
        for (int ep = 0; ep < 32; ++ep)
            acc += pool[OFF_WHH + ep * 32 + d] * pool[OFF_A12 + e * 32 + ep];
        pool[OFF_VWT + d * 96 + e] = acc;
    }
    __syncthreads();

    // ---- Setup S2: A12 / c12 (reads staged wts @CONVW, Mkq @KQ, MvW @VWT)
    for (int o = tid; o < 4096; o += 256) {
        int c = o >> 7, col = o & 127;
        float acc = 0.f;
        if (col < 32) {
#pragma unroll 8
            for (int d = 0; d < 32; ++d)
                acc += pool[OFF_CONVW + d * 32 + c] * pool[OFF_KQ + d * 32 + col];
        } else {
            int e = col - 32;
#pragma unroll 8
            for (int d = 0; d < 32; ++d)
                acc += pool[OFF_CONVW + d * 32 + c] * pool[OFF_VWT + d * 96 + e];
        }
        pool[OFF_A12 + c * 128 + col] = acc;
    }
    if (tid < 128) {
        int col = tid;
        float acc = 0.f;
        if (col < 32) {
            for (int d = 0; d < 32; ++d)
                acc += to_slot_b[d] * pool[OFF_KQ + d * 32 + col];
        } else {
            int e = col - 32;
            for (int d = 0; d < 32; ++d)
                acc += to_slot_b[d] * pool[OFF_VWT + d * 96 + e];
        }
        pool[OFF_C12 + col] = acc;
    }
    __syncthreads();

    // ---- Setup S3: real whh/convW (overwrite consumed staging), biases, X(0)
    for (int i = tid; i < 3072; i += 256)
        pool[OFF_WHH + (i >> 5) * 36 + (i & 31)] = whh[i];
    for (int i = tid; i < 1024; i += 256)
        pool[OFF_CONVW + (i >> 5) * 36 + (i & 31)] = conv_w[i];
    if (tid < 96) { pool[OFF_BIH + tid] = bih[tid]; pool[OFF_BHH + tid] = bhh[tid]; }

    auto load_X = [&](int idx, int step) {
        int i = idx >> 2, j4 = idx & 3;
        float4 c4 = *(const float4*)&fb[(size_t)(step + 1) * 256 + i * 16 + j4 * 4];
        float4 p4 = *(const float4*)&fb[(size_t)step * 256 + i * 16 + j4 * 4];
        int n = (i >> 2) * 4 + j4, p = i & 3;
        *(float4*)&pool[OFF_X + n * 36 + p * 4] = c4;
        *(float4*)&pool[OFF_X + n * 36 + 16 + p * 4] = p4;
    };
    if (tid < 64) load_X(tid, 0);

    float h0 = slot_mu[s_id * 32 + u];   // wave0 slot state (d=u, d=u+16)
    float h1 = slot_mu[s_id * 32 + u + 16];
    __syncthreads();

    // ---- Prologue: conv(step 0), all threads, weights from LDS
    {
        int o = tid & 31;
        const float* cvw = &pool[OFF_CONVW + o * 36];
        float cb = conv_b[o];
        for (int i = tid; i < 512; i += 256) {
            int n = i >> 5;
            const float* xr = &pool[OFF_X + n * 36];
            float acc = cb;
#pragma unroll
            for (int k = 0; k < 32; k += 4) {
                float4 w4 = *(const float4*)&cvw[k];
                float4 x4 = *(const float4*)&xr[k];
                acc += w4.x * x4.x + w4.y * x4.y + w4.z * x4.z + w4.w * x4.w;
            }
            pool[OFF_FEAT + n * 36 + o] = gelu_exact(acc);
        }
    }
    __syncthreads();

    // KQV GEMM task: task in [0,128): cols (c0,c0+1) x rows [r0,r0+8)
    auto gemm_task = [&](int task, float* kqb, float* vWTb) {
        int c0 = (task >> 1) << 1;
        int r0 = (task & 1) * 8;
        float accx[8], accy[8];
#pragma unroll
        for (int r = 0; r < 8; ++r) { accx[r] = 0.f; accy[r] = 0.f; }
#pragma unroll
        for (int c4 = 0; c4 < 8; ++c4) {
            float2 a0 = *(const float2*)&pool[OFF_A12 + (c4 * 4 + 0) * 128 + c0];
            float2 a1 = *(const float2*)&pool[OFF_A12 + (c4 * 4 + 1) * 128 + c0];
            float2 a2 = *(const float2*)&pool[OFF_A12 + (c4 * 4 + 2) * 128 + c0];
            float2 a3 = *(const float2*)&pool[OFF_A12 + (c4 * 4 + 3) * 128 + c0];
#pragma unroll
            for (int r = 0; r < 8; ++r) {
                float4 f = *(const float4*)&pool[OFF_FEAT + (r0 + r) * 36 + c4 * 4];
                accx[r] += f.x * a0.x + f.y * a1.x + f.z * a2.x + f.w * a3.x;
                accy[r] += f.x * a0.y + f.y * a1.y + f.z * a2.y + f.w * a3.y;
            }
        }
        float cx = pool[OFF_C12 + c0], cy = pool[OFF_C12 + c0 + 1];
        if (c0 < 32) {
#pragma unroll
            for (int r = 0; r < 8; ++r)
                *(float2*)&kqb[(r0 + r) * 36 + c0] =
                    make_float2(accx[r] + cx, accy[r] + cy);
        } else {
            int e0 = c0 - 32;
#pragma unroll
            for (int r = 0; r < 8; ++r) {
                vWTb[e0 * 20 + r0 + r] = accx[r] + cx;
                vWTb[(e0 + 1) * 20 + r0 + r] = accy[r] + cy;
            }
        }
    };

    // ---- Prologue: KQV(step 0) -> buffers[0]; X(step 1)
    if (tid < 128) gemm_task(tid, &pool[OFF_KQ], &pool[OFF_VWT]);
    else if (tid < 192) load_X(tid - 128, 1);
    __syncthreads();

    float* so = slots_out + (size_t)b * (126 * 128);
    int curb = 0;

    // wave-0 attention iteration: all cross-lane via shfl, no LDS writes
    auto attn_iter = [&](const float* kqb, const float* vWTb) {
        float sr[32];
#pragma unroll
        for (int k = 0; k < 16; ++k) sr[k] = __shfl(h0, s_id * 16 + k);
#pragma unroll
        for (int k = 0; k < 16; ++k) sr[16 + k] = __shfl(h1, s_id * 16 + k);
        // logits for n = u
        const float* kr = &kqb[u * 36];
        float lg = 0.f;
#pragma unroll
        for (int k = 0; k < 32; k += 4) {
            float4 kv = *(const float4*)&kr[k];
            lg += sr[k] * kv.x + sr[k + 1] * kv.y + sr[k + 2] * kv.z + sr[k + 3] * kv.w;
        }
        lg *= 0.17677669529663687f;   // 1/sqrt(32)
        float m = fmaxf(lg, __shfl_xor(lg, 16));
        m = fmaxf(m, __shfl_xor(m, 32));
        float e = __expf(lg - m);
        float ss = e + __shfl_xor(e, 16);
        ss += __shfl_xor(ss, 32);
        float at = e / ss;
        float gh[6];
#pragma unroll
        for (int j = 0; j < 6; ++j) {
            int ee = u + 16 * j;
            const float* wr = &pool[OFF_WHH + ee * 36];
            float acc = pool[OFF_BHH + ee];
#pragma unroll
            for (int k = 0; k < 32; k += 4) {
                float4 w4 = *(const float4*)&wr[k];
                acc += sr[k] * w4.x + sr[k + 1] * w4.y + sr[k + 2] * w4.z + sr[k + 3] * w4.w;
            }
            gh[j] = acc;
        }
        float ar[16];
#pragma unroll
        for (int n = 0; n < 16; ++n) ar[n] = __shfl(at, s_id * 16 + n);
        float gi[6];
#pragma unroll
        for (int j = 0; j < 6; ++j) {
            int ee = u + 16 * j;
            const float* vr = &vWTb[ee * 20];
            float acc = pool[OFF_BIH + ee];
#pragma unroll
            for (int n = 0; n < 16; n += 4) {
                float4 v4 = *(const float4*)&vr[n];
                acc += ar[n] * v4.x + ar[n + 1] * v4.y + ar[n + 2] * v4.z + ar[n + 3] * v4.w;
            }
            gi[j] = acc;
        }
        float rg0 = fast_sigmoid(gi[0] + gh[0]);
        float rg1 = fast_sigmoid(gi[1] + gh[1]);
        float zg0 = fast_sigmoid(gi[2] + gh[2]);
        float zg1 = fast_sigmoid(gi[3] + gh[3]);
        float ng0 = fast_tanh(gi[4] + rg0 * gh[4]);
        float ng1 = fast_tanh(gi[5] + rg1 * gh[5]);
        h0 = (1.f - zg0) * ng0 + zg0 * h0;
        h1 = (1.f - zg1) * ng1 + zg1 * h1;
    };

#pragma unroll 1
    for (int t = 0; t < 126; ++t) {
        const float* kqc = &pool[OFF_KQ + curb * 576];
        const float* vcur = &pool[OFF_VWT + curb * 1920];
        float* kqn = &pool[OFF_KQ + (curb ^ 1) * 576];
        float* vnxt = &pool[OFF_VWT + (curb ^ 1) * 1920];

        // ---- phase 1: wave0 iters 0,1 ; waves1-3 conv(t+1)
        if (wid == 0) {
            attn_iter(kqc, vcur);
            attn_iter(kqc, vcur);
        } else if (t < 125) {
            int o = tid1 & 31;
            const float* cvw = &pool[OFF_CONVW + o * 36];
            float cb = pool[OFF_CONVW + o * 36 + 32];  // unused slot? no:
            cb = conv_b[o];                             // L1-hot global read
            for (int i = tid1; i < 512; i += 192) {
                int n = i >> 5;
                const float* xr = &pool[OFF_X + n * 36];
                float acc = cb;
#pragma unroll
                for (int k = 0; k < 32; k += 4) {
                    float4 w4 = *(const float4*)&cvw[k];
                    float4 x4 = *(const float4*)&xr[k];
                    acc += w4.x * x4.x + w4.y * x4.y + w4.z * x4.z + w4.w * x4.w;
                }
                pool[OFF_FEAT + n * 36 + o] = gelu_exact(acc);
            }
        }
        __syncthreads();

        // ---- phase 2: wave0 iter 2 + store ; waves1-3 GEMM(t+1) + X(t+2)
        if (wid == 0) {
            attn_iter(kqc, vcur);
            so[t * 128 + s_id * 32 + u] = h0;
            so[t * 128 + s_id * 32 + u + 16] = h1;
        } else {
            if (tid1 < 128) {
                if (t < 125) gemm_task(tid1, kqn, vnxt);
            } else if (t < 124) {
                load_X(tid1 - 128, t + 2);
            }
        }
        __syncthreads();
        curb ^= 1;
    }
}

// ---------------------------------------------------------------------------
// Kernel B: batched decode. GEMM (64512 x 512) = slots_traj (64512 x 128) @
// dec_w^T, fused deconv(4x4,s4) + tanh + add curr + clip. 32 rows per block.
// ---------------------------------------------------------------------------
__global__ __launch_bounds__(TB, 1) void decode_kernel(
    const float* __restrict__ slots_traj, const float* __restrict__ frames,
    const float* __restrict__ dec_w, const float* __restrict__ dec_b,
    const float* __restrict__ deconv_w, const float* __restrict__ deconv_b,
    float* __restrict__ out)
{
    const int tid = threadIdx.x;
    const int m0 = blockIdx.x * 32;

    __shared__ float sl_s[32 * 132];
    __shared__ float wch_s[64 * 132];
    __shared__ float dw_s[512];
    __shared__ float db_s[512];

    for (int i = tid * 4; i < 32 * 128; i += TB * 4) {
        float4 v = *(const float4*)&slots_traj[(size_t)m0 * 128 + i];
        int r = i >> 7, k = i & 127;
        *(float4*)&sl_s[r * 132 + k] = v;
    }
    for (int i = tid; i < 512; i += TB) {
        dw_s[i] = deconv_w[i];
        db_s[i] = dec_b[i];
    }
    __syncthreads();

    const int cg = tid & 63;
    const int rg = tid >> 6;

    float acc[8][8];
#pragma unroll
    for (int ci = 0; ci < 8; ++ci)
#pragma unroll
        for (int rr = 0; rr < 8; ++rr) acc[ci][rr] = 0.f;

    const float* slb = &sl_s[(rg * 8) * 132];

#pragma unroll
    for (int ch = 0; ch < 8; ++ch) {
        for (int i = tid * 4; i < 64 * 128; i += TB * 4) {
            float4 v = *(const float4*)&dec_w[(size_t)ch * 8192 + i];
            int cl = i >> 7, k = i & 127;
            *(float4*)&wch_s[cl * 132 + k] = v;
        }
        __syncthreads();
        const float* wrow = &wch_s[cg * 132];
#pragma unroll 4
        for (int k = 0; k < 128; k += 4) {
            float4 w4 = *(const float4*)&wrow[k];
#pragma unroll
            for (int rr = 0; rr < 8; ++rr) {
                float4 s4 = *(const float4*)&slb[rr * 132 + k];
                acc[ch][rr] += w4.x * s4.x + w4.y * s4.y + w4.z * s4.z + w4.w * s4.w;
            }
        }
        __syncthreads();
    }

#pragma unroll
    for (int ci = 0; ci < 8; ++ci) {
        float bo = db_s[cg + 64 * ci];
#pragma unroll
        for (int rr = 0; rr < 8; ++rr) acc[ci][rr] += bo;
    }

    const int c0 = cg >> 4;
    const int sp = cg & 15;
    const int bi = sp >> 2, bj = sp & 3;
    const float db0 = deconv_b[0];

#pragma unroll 1
    for (int rr = 0; rr < 8; ++rr) {
        float part[16];
#pragma unroll
        for (int kl = 0; kl < 16; ++kl) part[kl] = 0.f;
#pragma unroll
        for (int m = 0; m < 8; ++m) {
            float sf = acc[m][rr];
            const float* dwp = &dw_s[(c0 + 4 * m) * 16];
#pragma unroll
            for (int kl = 0; kl < 16; ++kl) part[kl] += sf * dwp[kl];
        }
#pragma unroll
        for (int kl = 0; kl < 16; ++kl) {
            part[kl] += __shfl_xor(part[kl], 16);
            part[kl] += __shfl_xor(part[kl], 32);
        }
        if (c0 == 0) {
            int mrow = m0 + rg * 8 + rr;
            int bb = mrow / 126, tt = mrow - bb * 126;
            const float* fr = frames + ((size_t)bb * 128 + (tt + 1)) * 256;
            float* op = out + (size_t)mrow * 256;
#pragma unroll
            for (int kk = 0; kk < 4; ++kk) {
                int pixb = (bi * 4 + kk) * 16 + bj * 4;
                float4 c4 = *(const float4*)&fr[pixb];
                float4 o4;
                o4.x = fminf(fmaxf(c4.x + tanhf(part[kk * 4 + 0] + db0), 0.f), 1.f);
                o4.y = fminf(fmaxf(c4.y + tanhf(part[kk * 4 + 1] + db0), 0.f), 1.f);
                o4.z = fminf(fmaxf(c4.z + tanhf(part[kk * 4 + 2] + db0), 0.f), 1.f);
                o4.w = fminf(fmaxf(c4.w + tanhf(part[kk * 4 + 3] + db0), 0.f), 1.f);
                *(float4*)&op[pixb] = o4;
            }
        }
    }
}

extern "C" void kernel_launch(void* const* d_in, const int* in_sizes, int n_in,
                              void* d_out, int out_size, void* d_ws, size_t ws_size,
                              hipStream_t stream) {
    const float* frames    = (const float*)d_in[0];
    const float* slot_mu   = (const float*)d_in[1];
    const float* conv_w    = (const float*)d_in[2];
    const float* conv_b    = (const float*)d_in[3];
    const float* to_slot_w = (const float*)d_in[4];
    const float* to_slot_b = (const float*)d_in[5];
    const float* q_w       = (const float*)d_in[6];
    const float* k_w       = (const float*)d_in[7];
    const float* v_w       = (const float*)d_in[8];
    const float* gru_wih   = (const float*)d_in[9];
    const float* gru_whh   = (const float*)d_in[10];
    const float* gru_bih   = (const float*)d_in[11];
    const float* gru_bhh   = (const float*)d_in[12];
    const float* dec_w     = (const float*)d_in[13];
    const float* dec_b     = (const float*)d_in[14];
    const float* deconv_w  = (const float*)d_in[15];
    const float* deconv_b  = (const float*)d_in[16];

    float* slots_traj = (float*)d_ws;  // 512*126*128 floats = 33 MB
    float* outp = (float*)d_out;

    hipLaunchKernelGGL(slot_recur_pipe, dim3(512), dim3(256), 0, stream,
                       frames, slot_mu, conv_w, conv_b, to_slot_w, to_slot_b,
                       q_w, k_w, v_w, gru_wih, gru_whh, gru_bih, gru_bhh,
                       slots_traj);
    hipLaunchKernelGGL(decode_kernel, dim3(64512 / 32), dim3(TB), 0, stream,
                       slots_traj, frames, dec_w, dec_b, deconv_w, deconv_b,
                       outp);
}

// Round 6
// 1032.831 us; speedup vs baseline: 3.3332x; 1.8489x over previous
//
#include <hip/hip_runtime.h>
#include <math.h>

#define TB 256

__device__ __forceinline__ float fast_sigmoid(float x) {
    return 1.0f / (1.0f + __expf(-x));
}
__device__ __forceinline__ float fast_tanh(float x) {
    float a = fabsf(x);
    float e = __expf(2.0f * a);
    float r = 1.0f - 2.0f / (e + 1.0f);
    return copysignf(r, x);
}
__device__ __forceinline__ float gelu_exact(float x) {
    return 0.5f * x * (1.0f + erff(x * 0.70710678118654752f));
}

// Workspace layout (floats):
//   [0)                slots_traj : 64512*128  = 8,257,536
//   [SLOTS_N)          A12g       : 4224  (A12 [c][col] stride128 + c12[128])
//   [SLOTS_N+4224)     kqv        : 64512*2048 = 132,120,576
#define SLOTS_N 8257536ull
#define A12_OFF SLOTS_N
#define KQV_OFF (SLOTS_N + 4224ull)
#define WS_NEED_FLOATS (KQV_OFF + 132120576ull)

// ---------------------------------------------------------------------------
// K0: fused-weight setup (1 block). Writes A12 (4096, [c][col] stride 128)
// and c12 (128) to ws.
//   Mkq[d][dp] = sum_e k_w[e][d] q_w[e][dp]
//   MvW[d][e]  = sum_e' v_w[e'][d] wih[e][e']
//   A12[c][col] = sum_d wts[d][c] * (col<32 ? Mkq[d][col] : MvW[d][col-32])
//   c12[col]    = sum_d bts[d]   * (same)
// ---------------------------------------------------------------------------
__global__ __launch_bounds__(256, 1) void setup_fused(
    const float* __restrict__ to_slot_w, const float* __restrict__ to_slot_b,
    const float* __restrict__ q_w, const float* __restrict__ k_w,
    const float* __restrict__ v_w, const float* __restrict__ wih,
    float* __restrict__ A12g)
{
    const int tid = threadIdx.x;
    __shared__ float wih_s[3072], vkq_s[3072], wts_s[1024];
    __shared__ float mkq_s[1024], mvw_s[3072];

    for (int i = tid; i < 3072; i += 256) wih_s[i] = wih[i];
    for (int i = tid; i < 1024; i += 256) {
        vkq_s[i]        = v_w[i];
        vkq_s[1024 + i] = k_w[i];
        vkq_s[2048 + i] = q_w[i];
        wts_s[i]        = to_slot_w[i];
    }
    __syncthreads();
    for (int o = tid; o < 1024; o += 256) {
        int d = o >> 5, dp = o & 31;
        float acc = 0.f;
#pragma unroll 8
        for (int e = 0; e < 32; ++e)
            acc += vkq_s[1024 + e * 32 + d] * vkq_s[2048 + e * 32 + dp];
        mkq_s[o] = acc;
    }
    for (int o = tid; o < 3072; o += 256) {
        int d = o / 96, e = o - d * 96;
        float acc = 0.f;
#pragma unroll 8
        for (int ep = 0; ep < 32; ++ep)
            acc += vkq_s[ep * 32 + d] * wih_s[e * 32 + ep];
        mvw_s[d * 96 + e] = acc;
    }
    __syncthreads();
    for (int o = tid; o < 4096; o += 256) {
        int c = o >> 7, col = o & 127;
        float acc = 0.f;
        if (col < 32) {
#pragma unroll 8
            for (int d = 0; d < 32; ++d) acc += wts_s[d * 32 + c] * mkq_s[d * 32 + col];
        } else {
            int e = col - 32;
#pragma unroll 8
            for (int d = 0; d < 32; ++d) acc += wts_s[d * 32 + c] * mvw_s[d * 96 + e];
        }
        A12g[o] = acc;
    }
    if (tid < 128) {
        int col = tid;
        float acc = 0.f;
        if (col < 32) {
            for (int d = 0; d < 32; ++d) acc += to_slot_b[d] * mkq_s[d * 32 + col];
        } else {
            int e = col - 32;
            for (int d = 0; d < 32; ++d) acc += to_slot_b[d] * mvw_s[d * 96 + e];
        }
        A12g[4096 + col] = acc;
    }
}

// ---------------------------------------------------------------------------
// P: precompute kq/vWT for all (b,t). 8 pairs per 256-thread block.
// Per pair m = b*126+t: feat = gelu(conv(X)); [kq|vWT] = feat@A12 + c12.
// Output: kqv[m*2048 + n*32 + d] (kq, n<16,d<32);
//         kqv[m*2048 + 512 + e*16 + n] (vWT, e<96,n<16).
// ---------------------------------------------------------------------------
__global__ __launch_bounds__(256, 2) void precompute_kqv(
    const float* __restrict__ frames, const float* __restrict__ conv_w,
    const float* __restrict__ conv_b, const float* __restrict__ A12g,
    float* __restrict__ kqv)
{
    const int tid = threadIdx.x;
    const int m0 = blockIdx.x * 8;

    __shared__ float A12_s[4224];        // A12 [c][col] stride128 + c12 at 4096
    __shared__ float X_s[8][16 * 36];    // im2col [pair][n][k]
    __shared__ float feat_s[8][16 * 36]; // [pair][n][c]

    for (int i = tid; i < 4224; i += 256) A12_s[i] = A12g[i];

    // load frames -> X (32 threads per pair, 4 float4 each)
    {
        int pair = tid >> 5, fq = tid & 31;
        int m = m0 + pair, b = m / 126, t = m - b * 126;
        const float* base = frames + (size_t)b * 32768 + (size_t)t * 256;
#pragma unroll
        for (int k = 0; k < 4; ++k) {
            int f = fq + 32 * k;
            int h = f >> 6, rem = f & 63;
            int i = rem >> 2, j4 = rem & 3;
            // h=0: curr = frame t+1 ; h=1: prev = frame t
            float4 v = *(const float4*)&base[(h ? 0 : 256) + i * 16 + j4 * 4];
            int n = (i >> 2) * 4 + j4, pr = i & 3;
            *(float4*)&X_s[pair][n * 36 + h * 16 + pr * 4] = v;
        }
    }
    // conv weight row in regs
    const int o = tid & 31, g = tid >> 5;
    float cw[32];
    {
        const float* wp = conv_w + o * 32;
#pragma unroll
        for (int k = 0; k < 32; k += 4) {
            float4 v = *(const float4*)&wp[k];
            cw[k] = v.x; cw[k + 1] = v.y; cw[k + 2] = v.z; cw[k + 3] = v.w;
        }
    }
    const float cb = conv_b[o];
    __syncthreads();

    // conv + gelu: thread (o,g) does pairs 0..7? no: pair=g? 8 groups g==pair.
    // thread computes pair g, all 16 n? 16*32MAC*... -> assign: pair = g, n 0..15
    {
        int pair = g;
#pragma unroll
        for (int n = 0; n < 16; ++n) {
            const float* xr = &X_s[pair][n * 36];
            float acc = cb;
#pragma unroll
            for (int k = 0; k < 32; k += 4) {
                float4 x4 = *(const float4*)&xr[k];
                acc += cw[k] * x4.x + cw[k + 1] * x4.y + cw[k + 2] * x4.z + cw[k + 3] * x4.w;
            }
            feat_s[pair][n * 36 + o] = gelu_exact(acc);
        }
    }
    __syncthreads();

    // KQV GEMM: thread = (c0 = 2*(tid&63), pg = tid>>6); pairs pg*2, pg*2+1
    const int c0 = 2 * (tid & 63);
    const int pg = tid >> 6;
    const float cx = A12_s[4096 + c0], cy = A12_s[4096 + c0 + 1];

#pragma unroll
    for (int pp = 0; pp < 2; ++pp) {
        int pair = pg * 2 + pp;
        int m = m0 + pair;
        float accx[16], accy[16];
#pragma unroll
        for (int n = 0; n < 16; ++n) { accx[n] = 0.f; accy[n] = 0.f; }
#pragma unroll
        for (int c4 = 0; c4 < 8; ++c4) {
            float2 a0 = *(const float2*)&A12_s[(c4 * 4 + 0) * 128 + c0];
            float2 a1 = *(const float2*)&A12_s[(c4 * 4 + 1) * 128 + c0];
            float2 a2 = *(const float2*)&A12_s[(c4 * 4 + 2) * 128 + c0];
            float2 a3 = *(const float2*)&A12_s[(c4 * 4 + 3) * 128 + c0];
#pragma unroll
            for (int n = 0; n < 16; ++n) {
                float4 f = *(const float4*)&feat_s[pair][n * 36 + c4 * 4];
                accx[n] += f.x * a0.x + f.y * a1.x + f.z * a2.x + f.w * a3.x;
                accy[n] += f.x * a0.y + f.y * a1.y + f.z * a2.y + f.w * a3.y;
            }
        }
        float* outp = kqv + (size_t)m * 2048;
        if (c0 < 32) {
#pragma unroll
            for (int n = 0; n < 16; ++n)
                *(float2*)&outp[n * 32 + c0] = make_float2(accx[n] + cx, accy[n] + cy);
        } else {
            int e0 = c0 - 32;
#pragma unroll
            for (int n4 = 0; n4 < 4; ++n4) {
                *(float4*)&outp[512 + e0 * 16 + n4 * 4] =
                    make_float4(accx[n4 * 4] + cx, accx[n4 * 4 + 1] + cx,
                                accx[n4 * 4 + 2] + cx, accx[n4 * 4 + 3] + cx);
                *(float4*)&outp[512 + (e0 + 1) * 16 + n4 * 4] =
                    make_float4(accy[n4 * 4] + cy, accy[n4 * 4 + 1] + cy,
                                accy[n4 * 4 + 2] + cy, accy[n4 * 4 + 3] + cy);
            }
        }
    }
}

// ---------------------------------------------------------------------------
// S: slim sequential kernel. 512 blocks x 64 threads (1 wave, no barriers).
// Streams kq/vWT per step (global->reg prefetch, reg->LDS double buffer).
// Per step: 3x { logits+shfl-softmax; gh = slots@whh^T; gi = attn@vWT^T;
//               GRU combine }. Lane = (s = l>>4, u = l&15).
// ---------------------------------------------------------------------------
__global__ __launch_bounds__(64, 1) void slot_seq(
    const float* __restrict__ kqv, const float* __restrict__ slot_mu,
    const float* __restrict__ whh, const float* __restrict__ bih,
    const float* __restrict__ bhh, float* __restrict__ slots_out)
{
    const int l = threadIdx.x;
    const int b = blockIdx.x;
    const int s_id = l >> 4, u = l & 15;

    __shared__ float whh_s[96 * 36];
    __shared__ float bih_s[96], bhh_s[96];
    __shared__ float slots_s[4 * 36];
    __shared__ float attn_s[4 * 20];
    __shared__ float kq_s[2][16 * 36];
    __shared__ float vwt_s[2][96 * 20];

    // setup: whh (768 float4), biases, slots
    for (int idx = l; idx < 768; idx += 64) {
        int e = idx >> 3, d4 = idx & 7;
        *(float4*)&whh_s[e * 36 + d4 * 4] = *(const float4*)&whh[idx * 4];
    }
    for (int i = l; i < 96; i += 64) { bih_s[i] = bih[i]; bhh_s[i] = bhh[i]; }
    slots_s[s_id * 36 + u] = slot_mu[s_id * 32 + u];
    slots_s[s_id * 36 + u + 16] = slot_mu[s_id * 32 + u + 16];

    const float4* kb4 = (const float4*)(kqv + (size_t)b * 126 * 2048);
    float4 pf[8];

    // stage step 0 -> buf 0
#pragma unroll
    for (int k = 0; k < 8; ++k) pf[k] = kb4[l + 64 * k];
    // write map (static per k): k<2 -> kq, k>=2 -> vWT
#define WRITE_STAGE(BUF)                                                     \
    {                                                                        \
        _Pragma("unroll")                                                    \
        for (int k = 0; k < 2; ++k) {                                        \
            int flat = 4 * l + 256 * k;                                      \
            int n = flat >> 5, d = flat & 31;                                \
            *(float4*)&kq_s[BUF][n * 36 + d] = pf[k];                        \
        }                                                                    \
        _Pragma("unroll")                                                    \
        for (int k = 2; k < 8; ++k) {                                        \
            int q = 4 * l + 256 * (k - 2);                                   \
            int e = q >> 4, n4 = q & 15;                                     \
            *(float4*)&vwt_s[BUF][e * 20 + n4] = pf[k];                      \
        }                                                                    \
    }
    WRITE_STAGE(0)
    __syncthreads();   // single wave: lgkm drain only

    float* so = slots_out + (size_t)b * (126 * 128);
    int cur = 0;

#pragma unroll 1
    for (int t = 0; t < 126; ++t) {
        // prefetch t+1 into regs (lands during the 3 iterations)
        if (t < 125) {
            const float4* src = kb4 + (size_t)(t + 1) * 512;
#pragma unroll
            for (int k = 0; k < 8; ++k) pf[k] = src[l + 64 * k];
        }
        const float* kqc = kq_s[cur];
        const float* vwc = vwt_s[cur];

#pragma unroll 1
        for (int it = 0; it < 3; ++it) {
            // slots row -> regs (broadcast LDS reads)
            float sr[32];
#pragma unroll
            for (int k = 0; k < 32; k += 4) {
                float4 v = *(const float4*)&slots_s[s_id * 36 + k];
                sr[k] = v.x; sr[k + 1] = v.y; sr[k + 2] = v.z; sr[k + 3] = v.w;
            }
            float h0 = slots_s[s_id * 36 + u];
            float h1 = slots_s[s_id * 36 + u + 16];
            // logits (n = u) + softmax over slots via shfl
            {
                const float* kr = &kqc[u * 36];
                float lg = 0.f;
#pragma unroll
                for (int k = 0; k < 32; k += 4) {
                    float4 kv = *(const float4*)&kr[k];
                    lg += sr[k] * kv.x + sr[k + 1] * kv.y + sr[k + 2] * kv.z + sr[k + 3] * kv.w;
                }
                lg *= 0.17677669529663687f;  // 1/sqrt(32)
                float m = fmaxf(lg, __shfl_xor(lg, 16));
                m = fmaxf(m, __shfl_xor(m, 32));
                float e = __expf(lg - m);
                float ss = e + __shfl_xor(e, 16);
                ss += __shfl_xor(ss, 32);
                attn_s[s_id * 20 + u] = e / ss;
            }
            // gh
            float gh[6];
#pragma unroll
            for (int j = 0; j < 6; ++j) {
                int ee = u + 16 * j;
                const float* wr = &whh_s[ee * 36];
                float acc = bhh_s[ee];
#pragma unroll
                for (int k = 0; k < 32; k += 4) {
                    float4 w4 = *(const float4*)&wr[k];
                    acc += sr[k] * w4.x + sr[k + 1] * w4.y + sr[k + 2] * w4.z + sr[k + 3] * w4.w;
                }
                gh[j] = acc;
            }
            // attn row -> regs
            float ar[16];
#pragma unroll
            for (int k = 0; k < 16; k += 4) {
                float4 a4 = *(const float4*)&attn_s[s_id * 20 + k];
                ar[k] = a4.x; ar[k + 1] = a4.y; ar[k + 2] = a4.z; ar[k + 3] = a4.w;
            }
            // gi
            float gi[6];
#pragma unroll
            for (int j = 0; j < 6; ++j) {
                int ee = u + 16 * j;
                const float* vr = &vwc[ee * 20];
                float acc = bih_s[ee];
#pragma unroll
                for (int n = 0; n < 16; n += 4) {
                    float4 v4 = *(const float4*)&vr[n];
                    acc += ar[n] * v4.x + ar[n + 1] * v4.y + ar[n + 2] * v4.z + ar[n + 3] * v4.w;
                }
                gi[j] = acc;
            }
            // GRU combine
            float rg0 = fast_sigmoid(gi[0] + gh[0]);
            float rg1 = fast_sigmoid(gi[1] + gh[1]);
            float zg0 = fast_sigmoid(gi[2] + gh[2]);
            float zg1 = fast_sigmoid(gi[3] + gh[3]);
            float ng0 = fast_tanh(gi[4] + rg0 * gh[4]);
            float ng1 = fast_tanh(gi[5] + rg1 * gh[5]);
            float hn0 = (1.f - zg0) * ng0 + zg0 * h0;
            float hn1 = (1.f - zg1) * ng1 + zg1 * h1;
            slots_s[s_id * 36 + u] = hn0;
            slots_s[s_id * 36 + u + 16] = hn1;
            if (it == 2) {
                so[t * 128 + s_id * 32 + u] = hn0;
                so[t * 128 + s_id * 32 + u + 16] = hn1;
            }
        }
        // write prefetched next step into the other buffer
        if (t < 125) WRITE_STAGE(cur ^ 1)
        cur ^= 1;
    }
}

// ---------------------------------------------------------------------------
// FALLBACK kernel A (round-2 verified, 844 us): used when ws_size is too
// small for the precompute path.
// ---------------------------------------------------------------------------
__global__ __launch_bounds__(256, 2) void slot_recur_kernel(
    const float* __restrict__ frames, const float* __restrict__ slot_mu,
    const float* __restrict__ conv_w, const float* __restrict__ conv_b,
    const float* __restrict__ to_slot_w, const float* __restrict__ to_slot_b,
    const float* __restrict__ q_w, const float* __restrict__ k_w,
    const float* __restrict__ v_w,
    const float* __restrict__ wih, const float* __restrict__ whh,
    const float* __restrict__ bih, const float* __restrict__ bhh,
    float* __restrict__ slots_out)
{
    const int tid = threadIdx.x;
    const int b = blockIdx.x;
    const int lane = tid & 63;
    const int wid = tid >> 6;

    __shared__ float A12_s[32 * 132];
    __shared__ float c12_s[128];
    __shared__ float whh_s[96 * 36];
    __shared__ float vWT_s[96 * 20];
    __shared__ float kq_s[16 * 36];
    __shared__ float X_s[16 * 36];
    __shared__ float feat_s[16 * 36];
    __shared__ float slots_s[4 * 36];
    __shared__ float attn_s[4 * 20];
    __shared__ float bih_s[96], bhh_s[96];
    __shared__ float Mkq_s[1024];
    __shared__ float scr_s[32 * 96];
    __shared__ float gh_s[4 * 100], gi_s[4 * 100];

    for (int i = tid; i < 3072; i += 256) A12_s[i] = wih[i];
    for (int i = tid; i < 1024; i += 256) {
        whh_s[i]        = v_w[i];
        whh_s[1024 + i] = k_w[i];
        whh_s[2048 + i] = q_w[i];
        vWT_s[i]        = to_slot_w[i];
    }
    __syncthreads();
    for (int o = tid; o < 1024; o += 256) {
        int d = o >> 5, dp = o & 31;
        float acc = 0.f;
#pragma unroll 8
        for (int e = 0; e < 32; ++e)
            acc += whh_s[1024 + e * 32 + d] * whh_s[2048 + e * 32 + dp];
        Mkq_s[o] = acc;
    }
    for (int o = tid; o < 3072; o += 256) {
        int d = o / 96, e = o - d * 96;
        float acc = 0.f;
#pragma unroll 8
        for (int ep = 0; ep < 32; ++ep)
            acc += whh_s[ep * 32 + d] * A12_s[e * 32 + ep];
        scr_s[d * 96 + e] = acc;
    }
    __syncthreads();
    for (int o = tid; o < 4096; o += 256) {
        int c = o >> 7, col = o & 127;
        float acc = 0.f;
        if (col < 32) {
#pragma unroll 8
            for (int d = 0; d < 32; ++d) acc += vWT_s[d * 32 + c] * Mkq_s[d * 32 + col];
        } else {
            int e = col - 32;
#pragma unroll 8
            for (int d = 0; d < 32; ++d) acc += vWT_s[d * 32 + c] * scr_s[d * 96 + e];
        }
        A12_s[c * 132 + col] = acc;
    }
    if (tid < 128) {
        int col = tid;
        float acc = 0.f;
        if (col < 32) {
            for (int d = 0; d < 32; ++d) acc += to_slot_b[d] * Mkq_s[d * 32 + col];
        } else {
            int e = col - 32;
            for (int d = 0; d < 32; ++d) acc += to_slot_b[d] * scr_s[d * 96 + e];
        }
        c12_s[col] = acc;
    }
    for (int i = tid; i < 3072; i += 256) whh_s[(i >> 5) * 36 + (i & 31)] = whh[i];
    if (tid < 96) { bih_s[tid] = bih[tid]; bhh_s[tid] = bhh[tid]; }
    if (tid < 128) slots_s[(tid >> 5) * 36 + (tid & 31)] = slot_mu[tid];

    const float* fb = frames + (size_t)b * (128 * 256);
    if (tid < 128) {
        int h = tid >> 6, ll = tid & 63;
        int i = ll >> 2, j4 = ll & 3;
        float4 v = *(const float4*)&fb[(h ? 0 : 256) + i * 16 + j4 * 4];
        int n = (i >> 2) * 4 + j4, p = i & 3;
        *(float4*)&X_s[n * 36 + h * 16 + p * 4] = v;
    }
    __syncthreads();

    float* so = slots_out + (size_t)b * (126 * 128);
    const int s_id = lane >> 4, u = lane & 15;

#pragma unroll 1
    for (int t = 0; t < 126; ++t) {
        {
            int o = tid & 31, ng = tid >> 5;
            const float* w = conv_w + o * 32;
            float acca = conv_b[o], accb = acca;
            const float* xa = &X_s[ng * 36];
            const float* xb = &X_s[(ng + 8) * 36];
#pragma unroll
            for (int k = 0; k < 32; k += 4) {
                float4 w4 = *(const float4*)&w[k];
                float4 a4 = *(const float4*)&xa[k];
                float4 b4 = *(const float4*)&xb[k];
                acca += w4.x * a4.x + w4.y * a4.y + w4.z * a4.z + w4.w * a4.w;
                accb += w4.x * b4.x + w4.y * b4.y + w4.z * b4.z + w4.w * b4.w;
            }
            feat_s[ng * 36 + o] = gelu_exact(acca);
            feat_s[(ng + 8) * 36 + o] = gelu_exact(accb);
        }
        __syncthreads();

        float4 pf;
        const bool havepf = (t < 125) && (tid < 128);
        if (havepf) {
            int h = tid >> 6, ll = tid & 63;
            int i = ll >> 2, j4 = ll & 3;
            pf = *(const float4*)&fb[(t + (h ? 1 : 2)) * 256 + i * 16 + j4 * 4];
        }
        {
            const int cg = tid & 63;
            const int wv = tid >> 6;
            const int col0 = cg * 2;
            float accx[4], accy[4];
#pragma unroll
            for (int j = 0; j < 4; ++j) { accx[j] = 0.f; accy[j] = 0.f; }
#pragma unroll
            for (int c = 0; c < 32; c += 4) {
                float2 a0 = *(const float2*)&A12_s[(c + 0) * 132 + col0];
                float2 a1 = *(const float2*)&A12_s[(c + 1) * 132 + col0];
                float2 a2 = *(const float2*)&A12_s[(c + 2) * 132 + col0];
                float2 a3 = *(const float2*)&A12_s[(c + 3) * 132 + col0];
#pragma unroll
                for (int j = 0; j < 4; ++j) {
                    float4 q = *(const float4*)&feat_s[(wv * 4 + j) * 36 + c];
                    accx[j] += a0.x * q.x + a1.x * q.y + a2.x * q.z + a3.x * q.w;
                    accy[j] += a0.y * q.x + a1.y * q.y + a2.y * q.z + a3.y * q.w;
                }
            }
            float cx = c12_s[col0], cy = c12_s[col0 + 1];
#pragma unroll
            for (int j = 0; j < 4; ++j) {
                int n = wv * 4 + j;
                float vx = accx[j] + cx, vy = accy[j] + cy;
                if (col0 < 32) {
                    *(float2*)&kq_s[n * 36 + col0] = make_float2(vx, vy);
                } else {
                    vWT_s[(col0 - 32) * 20 + n] = vx;
                    vWT_s[(col0 - 31) * 20 + n] = vy;
                }
            }
        }
        if (havepf) {
            int h = tid >> 6, ll = tid & 63;
            int i = ll >> 2, j4 = ll & 3;
            int n = (i >> 2) * 4 + j4, p = i & 3;
            *(float4*)&X_s[n * 36 + h * 16 + p * 4] = pf;
        }
        __syncthreads();

#pragma unroll 1
        for (int it = 0; it < 3; ++it) {
            if (wid == 0) {
                int s = lane >> 4, n = lane & 15;
                const float* sp = &slots_s[s * 36];
                const float* kp = &kq_s[n * 36];
                float acc = 0.f;
#pragma unroll
                for (int d = 0; d < 32; d += 4) {
                    float4 a = *(const float4*)&sp[d];
                    float4 c = *(const float4*)&kp[d];
                    acc += a.x * c.x + a.y * c.y + a.z * c.z + a.w * c.w;
                }
                float lg = acc * 0.17677669529663687f;
                float m = fmaxf(lg, __shfl_xor(lg, 16));
                m = fmaxf(m, __shfl_xor(m, 32));
                float e = __expf(lg - m);
                float ssum = e + __shfl_xor(e, 16);
                ssum += __shfl_xor(ssum, 32);
                attn_s[s * 20 + n] = e / ssum;
            } else {
                int idx = tid - 64;
                int sh = idx / 96;
                int e = idx - sh * 96;
                int s0 = sh * 2;
                const float* w = &whh_s[e * 36];
                const float* sa = &slots_s[s0 * 36];
                const float* sb = &slots_s[(s0 + 1) * 36];
                float acc0 = bhh_s[e], acc1 = acc0;
#pragma unroll
                for (int d = 0; d < 32; d += 4) {
                    float4 w4 = *(const float4*)&w[d];
                    float4 a4 = *(const float4*)&sa[d];
                    float4 b4 = *(const float4*)&sb[d];
                    acc0 += w4.x * a4.x + w4.y * a4.y + w4.z * a4.z + w4.w * a4.w;
                    acc1 += w4.x * b4.x + w4.y * b4.y + w4.z * b4.z + w4.w * b4.w;
                }
                gh_s[s0 * 100 + e] = acc0;
                gh_s[(s0 + 1) * 100 + e] = acc1;
            }
            __syncthreads();
            if (tid < 192) {
                int sh = tid / 96;
                int e = tid - sh * 96;
                int s0 = sh * 2;
                const float* vp = &vWT_s[e * 20];
                const float* a0 = &attn_s[s0 * 20];
                const float* a1 = &attn_s[(s0 + 1) * 20];
                float g0 = bih_s[e], g1 = g0;
#pragma unroll
                for (int n = 0; n < 16; n += 4) {
                    float4 v4 = *(const float4*)&vp[n];
                    float4 x0 = *(const float4*)&a0[n];
                    float4 x1 = *(const float4*)&a1[n];
                    g0 += v4.x * x0.x + v4.y * x0.y + v4.z * x0.z + v4.w * x0.w;
                    g1 += v4.x * x1.x + v4.y * x1.y + v4.z * x1.z + v4.w * x1.w;
                }
                gi_s[s0 * 100 + e] = g0;
                gi_s[(s0 + 1) * 100 + e] = g1;
            }
            __syncthreads();
            if (tid < 128) {
                int s = tid >> 5, d = tid & 31;
                float gir = gi_s[s * 100 + d],      ghr = gh_s[s * 100 + d];
                float giz = gi_s[s * 100 + 32 + d], ghz = gh_s[s * 100 + 32 + d];
                float gin = gi_s[s * 100 + 64 + d], ghn = gh_s[s * 100 + 64 + d];
                float r = fast_sigmoid(gir + ghr);
                float z = fast_sigmoid(giz + ghz);
                float nn = fast_tanh(gin + r * ghn);
                float h = slots_s[s * 36 + d];
                float hn = (1.0f - z) * nn + z * h;
                slots_s[s * 36 + d] = hn;
                if (it == 2) so[t * 128 + tid] = hn;
            }
            __syncthreads();
        }
    }
}

// ---------------------------------------------------------------------------
// Kernel B: batched decode (unchanged, verified).
// ---------------------------------------------------------------------------
__global__ __launch_bounds__(TB, 1) void decode_kernel(
    const float* __restrict__ slots_traj, const float* __restrict__ frames,
    const float* __restrict__ dec_w, const float* __restrict__ dec_b,
    const float* __restrict__ deconv_w, const float* __restrict__ deconv_b,
    float* __restrict__ out)
{
    const int tid = threadIdx.x;
    const int m0 = blockIdx.x * 32;

    __shared__ float sl_s[32 * 132];
    __shared__ float wch_s[64 * 132];
    __shared__ float dw_s[512];
    __shared__ float db_s[512];

    for (int i = tid * 4; i < 32 * 128; i += TB * 4) {
        float4 v = *(const float4*)&slots_traj[(size_t)m0 * 128 + i];
        int r = i >> 7, k = i & 127;
        *(float4*)&sl_s[r * 132 + k] = v;
    }
    for (int i = tid; i < 512; i += TB) {
        dw_s[i] = deconv_w[i];
        db_s[i] = dec_b[i];
    }
    __syncthreads();

    const int cg = tid & 63;
    const int rg = tid >> 6;

    float acc[8][8];
#pragma unroll
    for (int ci = 0; ci < 8; ++ci)
#pragma unroll
        for (int rr = 0; rr < 8; ++rr) acc[ci][rr] = 0.f;

    const float* slb = &sl_s[(rg * 8) * 132];

#pragma unroll
    for (int ch = 0; ch < 8; ++ch) {
        for (int i = tid * 4; i < 64 * 128; i += TB * 4) {
            float4 v = *(const float4*)&dec_w[(size_t)ch * 8192 + i];
            int cl = i >> 7, k = i & 127;
            *(float4*)&wch_s[cl * 132 + k] = v;
        }
        __syncthreads();
        const float* wrow = &wch_s[cg * 132];
#pragma unroll 4
        for (int k = 0; k < 128; k += 4) {
            float4 w4 = *(const float4*)&wrow[k];
#pragma unroll
            for (int rr = 0; rr < 8; ++rr) {
                float4 s4 = *(const float4*)&slb[rr * 132 + k];
                acc[ch][rr] += w4.x * s4.x + w4.y * s4.y + w4.z * s4.z + w4.w * s4.w;
            }
        }
        __syncthreads();
    }

#pragma unroll
    for (int ci = 0; ci < 8; ++ci) {
        float bo = db_s[cg + 64 * ci];
#pragma unroll
        for (int rr = 0; rr < 8; ++rr) acc[ci][rr] += bo;
    }

    const int c0 = cg >> 4;
    const int sp = cg & 15;
    const int bi = sp >> 2, bj = sp & 3;
    const float db0 = deconv_b[0];

#pragma unroll 1
    for (int rr = 0; rr < 8; ++rr) {
        float part[16];
#pragma unroll
        for (int kl = 0; kl < 16; ++kl) part[kl] = 0.f;
#pragma unroll
        for (int m = 0; m < 8; ++m) {
            float sf = acc[m][rr];
            const float* dwp = &dw_s[(c0 + 4 * m) * 16];
#pragma unroll
            for (int kl = 0; kl < 16; ++kl) part[kl] += sf * dwp[kl];
        }
#pragma unroll
        for (int kl = 0; kl < 16; ++kl) {
            part[kl] += __shfl_xor(part[kl], 16);
            part[kl] += __shfl_xor(part[kl], 32);
        }
        if (c0 == 0) {
            int mrow = m0 + rg * 8 + rr;
            int bb = mrow / 126, tt = mrow - bb * 126;
            const float* fr = frames + ((size_t)bb * 128 + (tt + 1)) * 256;
            float* op = out + (size_t)mrow * 256;
#pragma unroll
            for (int kk = 0; kk < 4; ++kk) {
                int pixb = (bi * 4 + kk) * 16 + bj * 4;
                float4 c4 = *(const float4*)&fr[pixb];
                float4 o4;
                o4.x = fminf(fmaxf(c4.x + tanhf(part[kk * 4 + 0] + db0), 0.f), 1.f);
                o4.y = fminf(fmaxf(c4.y + tanhf(part[kk * 4 + 1] + db0), 0.f), 1.f);
                o4.z = fminf(fmaxf(c4.z + tanhf(part[kk * 4 + 2] + db0), 0.f), 1.f);
                o4.w = fminf(fmaxf(c4.w + tanhf(part[kk * 4 + 3] + db0), 0.f), 1.f);
                *(float4*)&op[pixb] = o4;
            }
        }
    }
}

extern "C" void kernel_launch(void* const* d_in, const int* in_sizes, int n_in,
                              void* d_out, int out_size, void* d_ws, size_t ws_size,
                              hipStream_t stream) {
    const float* frames    = (const float*)d_in[0];
    const float* slot_mu   = (const float*)d_in[1];
    const float* conv_w    = (const float*)d_in[2];
    const float* conv_b    = (const float*)d_in[3];
    const float* to_slot_w = (const float*)d_in[4];
    const float* to_slot_b = (const float*)d_in[5];
    const float* q_w       = (const float*)d_in[6];
    const float* k_w       = (const float*)d_in[7];
    const float* v_w       = (const float*)d_in[8];
    const float* gru_wih   = (const float*)d_in[9];
    const float* gru_whh   = (const float*)d_in[10];
    const float* gru_bih   = (const float*)d_in[11];
    const float* gru_bhh   = (const float*)d_in[12];
    const float* dec_w     = (const float*)d_in[13];
    const float* dec_b     = (const float*)d_in[14];
    const float* deconv_w  = (const float*)d_in[15];
    const float* deconv_b  = (const float*)d_in[16];

    float* ws = (float*)d_ws;
    float* slots_traj = ws;                 // 33 MB
    float* A12g       = ws + A12_OFF;
    float* kqv        = ws + KQV_OFF;
    float* outp = (float*)d_out;

    if (ws_size >= WS_NEED_FLOATS * 4ull) {
        hipLaunchKernelGGL(setup_fused, dim3(1), dim3(256), 0, stream,
                           to_slot_w, to_slot_b, q_w, k_w, v_w, gru_wih, A12g);
        hipLaunchKernelGGL(precompute_kqv, dim3(64512 / 8), dim3(256), 0, stream,
                           frames, conv_w, conv_b, A12g, kqv);
        hipLaunchKernelGGL(slot_seq, dim3(512), dim3(64), 0, stream,
                           kqv, slot_mu, gru_whh, gru_bih, gru_bhh, slots_traj);
    } else {
        hipLaunchKernelGGL(slot_recur_kernel, dim3(512), dim3(256), 0, stream,
                           frames, slot_mu, conv_w, conv_b, to_slot_w, to_slot_b,
                           q_w, k_w, v_w, gru_wih, gru_whh, gru_bih, gru_bhh,
                           slots_traj);
    }
    hipLaunchKernelGGL(decode_kernel, dim3(64512 / 32), dim3(TB), 0, stream,
                       slots_traj, frames, dec_w, dec_b, deconv_w, deconv_b,
                       outp);
}